// Round 1
// baseline (778.964 us; speedup 1.0000x reference)
//
#include <hip/hip_runtime.h>
#include <hip/hip_fp16.h>
#include <math.h>

typedef _Float16 half_t;
typedef _Float16 half8 __attribute__((ext_vector_type(8)));
typedef float f32x4 __attribute__((ext_vector_type(4)));

#define MFMA(a, b, c) __builtin_amdgcn_mfma_f32_16x16x32_f16((a), (b), (c), 0, 0, 0)

static constexpr int kC = 96;
static constexpr int kM = 262144;  // total tokens = 64 * 64 * 64
static constexpr float kScale = 0.2041241452319315f;  // 24^-0.5

// ws layout (bytes)
static constexpr size_t OFF_W = 0;                          // fp16 weights (221184 B)
static constexpr size_t OFF_A = 1u << 20;                   // slot A: 50331648 B (hwin / attnout / xnorm)
static constexpr size_t OFF_B = (1u << 20) + 50331648u;     // slot B: qkv f16, 150994944 B
static constexpr size_t WS_NEEDED = OFF_B + 150994944u;

// ---------------------------------------------------------------- weights -> fp16
__global__ __launch_bounds__(256) void k_convert(const float* __restrict__ qkv_w,
                                                 const float* __restrict__ proj_w,
                                                 const float* __restrict__ fc1_w,
                                                 const float* __restrict__ fc2_w,
                                                 half_t* __restrict__ wbuf) {
  int i = blockIdx.x * 256 + threadIdx.x;  // grid covers exactly 110592
  if (i < 27648)       wbuf[i] = (half_t)qkv_w[i];
  else if (i < 36864)  wbuf[i] = (half_t)proj_w[i - 27648];
  else if (i < 73728)  wbuf[i] = (half_t)fc1_w[i - 36864];
  else                 wbuf[i] = (half_t)fc2_w[i - 73728];
}

// ------------------------------------------- LN1 + roll(-4,-4) + window partition
__global__ __launch_bounds__(256) void k_ln1(const float* __restrict__ x,
                                             const float* __restrict__ gam,
                                             const float* __restrict__ bet,
                                             half_t* __restrict__ hwin) {
  int gid = blockIdx.x * 256 + threadIdx.x;  // output token: win*64 + tok
  int win = gid >> 6, tok = gid & 63;
  int bb = win >> 6, wh = (win >> 3) & 7, ww = win & 7;
  int ti = tok >> 3, tj = tok & 7;
  int sr = (wh * 8 + ti + 4) & 63, sc = (ww * 8 + tj + 4) & 63;
  const float4* xp = (const float4*)(x + ((size_t)bb * 4096 + sr * 64 + sc) * kC);
  float v[96];
  float mu = 0.f;
#pragma unroll
  for (int c = 0; c < 24; ++c) {
    float4 t = xp[c];
    v[4 * c + 0] = t.x; v[4 * c + 1] = t.y; v[4 * c + 2] = t.z; v[4 * c + 3] = t.w;
    mu += t.x + t.y + t.z + t.w;
  }
  mu *= (1.f / 96.f);
  float var = 0.f;
#pragma unroll
  for (int c = 0; c < 96; ++c) { float d = v[c] - mu; var += d * d; }
  float inv = rsqrtf(var * (1.f / 96.f) + 1e-5f);
  half_t* op = hwin + (size_t)gid * kC;
#pragma unroll
  for (int c0 = 0; c0 < 96; c0 += 8) {
    half8 h;
#pragma unroll
    for (int j = 0; j < 8; ++j)
      h[j] = (half_t)((v[c0 + j] - mu) * inv * gam[c0 + j] + bet[c0 + j]);
    *(half8*)(op + c0) = h;
  }
}

// ----------------------------------------------------- LN2 (natural token order)
__global__ __launch_bounds__(256) void k_ln2(const float* __restrict__ x,
                                             const float* __restrict__ gam,
                                             const float* __restrict__ bet,
                                             half_t* __restrict__ xnorm) {
  int gid = blockIdx.x * 256 + threadIdx.x;
  const float4* xp = (const float4*)(x + (size_t)gid * kC);
  float v[96];
  float mu = 0.f;
#pragma unroll
  for (int c = 0; c < 24; ++c) {
    float4 t = xp[c];
    v[4 * c + 0] = t.x; v[4 * c + 1] = t.y; v[4 * c + 2] = t.z; v[4 * c + 3] = t.w;
    mu += t.x + t.y + t.z + t.w;
  }
  mu *= (1.f / 96.f);
  float var = 0.f;
#pragma unroll
  for (int c = 0; c < 96; ++c) { float d = v[c] - mu; var += d * d; }
  float inv = rsqrtf(var * (1.f / 96.f) + 1e-5f);
  half_t* op = xnorm + (size_t)gid * kC;
#pragma unroll
  for (int c0 = 0; c0 < 96; c0 += 8) {
    half8 h;
#pragma unroll
    for (int j = 0; j < 8; ++j)
      h[j] = (half_t)((v[c0 + j] - mu) * inv * gam[c0 + j] + bet[c0 + j]);
    *(half8*)(op + c0) = h;
  }
}

// ------------------------------------------------------------------- QKV GEMM
// out(M,288) = hwin(M,96) @ qkv_w(288,96)^T + b ; grid.y = slice (q/k/v, 96 cols)
__global__ __launch_bounds__(256) void k_qkv(const half_t* __restrict__ hwin,
                                             const half_t* __restrict__ w16,
                                             const float* __restrict__ qkv_b,
                                             half_t* __restrict__ qkv) {
  int wave = threadIdx.x >> 6, lane = threadIdx.x & 63;
  int l15 = lane & 15, quad = lane >> 4;
  int s = blockIdx.y;
  int rowbase = (blockIdx.x * 4 + wave) * 64;
  half8 bf[6][3];
#pragma unroll
  for (int nt = 0; nt < 6; ++nt)
#pragma unroll
    for (int kt = 0; kt < 3; ++kt)
      bf[nt][kt] = *(const half8*)(w16 + (size_t)(s * 96 + nt * 16 + l15) * 96 + kt * 32 + quad * 8);
  half8 af[4][3];
#pragma unroll
  for (int g = 0; g < 4; ++g)
#pragma unroll
    for (int kt = 0; kt < 3; ++kt)
      af[g][kt] = *(const half8*)(hwin + (size_t)(rowbase + g * 16 + l15) * 96 + kt * 32 + quad * 8);
  float scale = (s == 0) ? kScale : 1.f;
#pragma unroll
  for (int nt = 0; nt < 6; ++nt) {
    f32x4 acc[4] = {{0.f, 0.f, 0.f, 0.f}, {0.f, 0.f, 0.f, 0.f}, {0.f, 0.f, 0.f, 0.f}, {0.f, 0.f, 0.f, 0.f}};
#pragma unroll
    for (int kt = 0; kt < 3; ++kt)
#pragma unroll
      for (int g = 0; g < 4; ++g)
        acc[g] = MFMA(af[g][kt], bf[nt][kt], acc[g]);
    int col = s * 96 + nt * 16 + l15;
    float bias = qkv_b[col];
#pragma unroll
    for (int g = 0; g < 4; ++g)
#pragma unroll
      for (int r = 0; r < 4; ++r) {
        int row = rowbase + g * 16 + quad * 4 + r;
        qkv[(size_t)row * 288 + col] = (half_t)((acc[g][r] + bias) * scale);
      }
  }
}

// ----------------------------------------------------- attention: wave per (win, head)
__global__ __launch_bounds__(64) void k_attn(const half_t* __restrict__ qkv,
                                             const float* __restrict__ bias_table,
                                             half_t* __restrict__ attnout) {
  __shared__ float kk[64][25];
  __shared__ float vv[64][25];
  __shared__ float tbl[225];
  int lane = threadIdx.x;
  int win = blockIdx.x >> 2, head = blockIdx.x & 3;
  const half_t* base = qkv + (size_t)win * 64 * 288;
#pragma unroll
  for (int c = 0; c < 24; ++c) {
    kk[lane][c] = (float)base[lane * 288 + 96 + head * 24 + c];
    vv[lane][c] = (float)base[lane * 288 + 192 + head * 24 + c];
  }
  for (int idx = lane; idx < 225; idx += 64) tbl[idx] = bias_table[idx * 4 + head];
  float q[24];
#pragma unroll
  for (int c = 0; c < 24; ++c) q[c] = (float)base[lane * 288 + head * 24 + c];
  __syncthreads();

  int wh = (win >> 3) & 7, ww = win & 7;
  int ih = lane >> 3, iw = lane & 7;
  int rr = wh * 8 + ih, cc = ww * 8 + iw;
  int regi = ((rr < 56) ? 0 : ((rr < 60) ? 1 : 2)) * 3 + ((cc < 56) ? 0 : ((cc < 60) ? 1 : 2));

  float s[64];
#pragma unroll
  for (int j = 0; j < 64; ++j) {
    float d = 0.f;
#pragma unroll
    for (int c = 0; c < 24; ++c) d += q[c] * kk[j][c];
    int jh = j >> 3, jw = j & 7;
    d += tbl[(ih - jh + 7) * 15 + (iw - jw + 7)];
    int rj = wh * 8 + jh, cj = ww * 8 + jw;
    int regj = ((rj < 56) ? 0 : ((rj < 60) ? 1 : 2)) * 3 + ((cj < 56) ? 0 : ((cj < 60) ? 1 : 2));
    if (regi != regj) d -= 100.f;
    s[j] = d;
  }
  float m = -1e30f;
#pragma unroll
  for (int j = 0; j < 64; ++j) m = fmaxf(m, s[j]);
  float sum = 0.f;
#pragma unroll
  for (int j = 0; j < 64; ++j) { s[j] = __expf(s[j] - m); sum += s[j]; }
  float inv = 1.f / sum;
  float o[24];
#pragma unroll
  for (int c = 0; c < 24; ++c) o[c] = 0.f;
#pragma unroll
  for (int j = 0; j < 64; ++j) {
    float p = s[j];
#pragma unroll
    for (int c = 0; c < 24; ++c) o[c] += p * vv[j][c];
  }
  half_t* op = attnout + ((size_t)win * 64 + lane) * 96 + head * 24;
#pragma unroll
  for (int c = 0; c < 24; ++c) op[c] = (half_t)(o[c] * inv);
}

// -------------------------- proj GEMM + window reverse + unshift + residual -> d_out
__global__ __launch_bounds__(256) void k_proj(const half_t* __restrict__ attnout,
                                              const half_t* __restrict__ w16,
                                              const float* __restrict__ proj_b,
                                              const float* __restrict__ x,
                                              float* __restrict__ out) {
  int wave = threadIdx.x >> 6, lane = threadIdx.x & 63;
  int l15 = lane & 15, quad = lane >> 4;
  int rowbase = (blockIdx.x * 4 + wave) * 64;
  half8 bf[6][3];
#pragma unroll
  for (int nt = 0; nt < 6; ++nt)
#pragma unroll
    for (int kt = 0; kt < 3; ++kt)
      bf[nt][kt] = *(const half8*)(w16 + (size_t)(nt * 16 + l15) * 96 + kt * 32 + quad * 8);
  half8 af[4][3];
#pragma unroll
  for (int g = 0; g < 4; ++g)
#pragma unroll
    for (int kt = 0; kt < 3; ++kt)
      af[g][kt] = *(const half8*)(attnout + (size_t)(rowbase + g * 16 + l15) * 96 + kt * 32 + quad * 8);
#pragma unroll
  for (int nt = 0; nt < 6; ++nt) {
    f32x4 acc[4] = {{0.f, 0.f, 0.f, 0.f}, {0.f, 0.f, 0.f, 0.f}, {0.f, 0.f, 0.f, 0.f}, {0.f, 0.f, 0.f, 0.f}};
#pragma unroll
    for (int kt = 0; kt < 3; ++kt)
#pragma unroll
      for (int g = 0; g < 4; ++g)
        acc[g] = MFMA(af[g][kt], bf[nt][kt], acc[g]);
    int col = nt * 16 + l15;
    float bias = proj_b[col];
#pragma unroll
    for (int g = 0; g < 4; ++g)
#pragma unroll
      for (int r = 0; r < 4; ++r) {
        int row = rowbase + g * 16 + quad * 4 + r;
        int win = row >> 6, tok = row & 63;
        int bb = win >> 6, wh = (win >> 3) & 7, ww = win & 7;
        int ti = tok >> 3, tj = tok & 7;
        int pr = (wh * 8 + ti + 4) & 63, pc = (ww * 8 + tj + 4) & 63;
        size_t fidx = ((size_t)bb * 4096 + pr * 64 + pc) * kC + col;
        out[fidx] = x[fidx] + acc[g][r] + bias;
      }
  }
}

// ------------------------------- fused MLP: fc1 + GELU(exact) + fc2 + residual RMW
__global__ __launch_bounds__(256) void k_mlp(const half_t* __restrict__ xnorm,
                                             const half_t* __restrict__ fc1w,
                                             const float* __restrict__ fc1b,
                                             const half_t* __restrict__ fc2w,
                                             const float* __restrict__ fc2b,
                                             float* __restrict__ out) {
  __shared__ __attribute__((aligned(16))) half_t h1[64 * 392];  // stride 392 halves (pad)
  int wave = threadIdx.x >> 6, lane = threadIdx.x & 63;
  int l15 = lane & 15, quad = lane >> 4;
  int rowbase = blockIdx.x * 64;
  // ---- fc1: this wave computes cols [wave*96, wave*96+96) for all 64 tokens
  half8 af[4][3];
#pragma unroll
  for (int g = 0; g < 4; ++g)
#pragma unroll
    for (int kt = 0; kt < 3; ++kt)
      af[g][kt] = *(const half8*)(xnorm + (size_t)(rowbase + g * 16 + l15) * 96 + kt * 32 + quad * 8);
#pragma unroll
  for (int nt = 0; nt < 6; ++nt) {
    f32x4 acc[4] = {{0.f, 0.f, 0.f, 0.f}, {0.f, 0.f, 0.f, 0.f}, {0.f, 0.f, 0.f, 0.f}, {0.f, 0.f, 0.f, 0.f}};
    int n0 = wave * 96 + nt * 16 + l15;
#pragma unroll
    for (int kt = 0; kt < 3; ++kt) {
      half8 bf = *(const half8*)(fc1w + (size_t)n0 * 96 + kt * 32 + quad * 8);
#pragma unroll
      for (int g = 0; g < 4; ++g) acc[g] = MFMA(af[g][kt], bf, acc[g]);
    }
    float bias = fc1b[n0];
#pragma unroll
    for (int g = 0; g < 4; ++g)
#pragma unroll
      for (int r = 0; r < 4; ++r) {
        float vv = acc[g][r] + bias;
        vv = 0.5f * vv * (1.f + erff(vv * 0.70710678118f));
        int row = g * 16 + quad * 4 + r;
        h1[row * 392 + n0] = (half_t)vv;
      }
  }
  __syncthreads();
  // ---- fc2: this wave computes rows [wave*16, wave*16+16), all 96 cols
  half8 a2[12];
#pragma unroll
  for (int kt = 0; kt < 12; ++kt)
    a2[kt] = *(const half8*)(&h1[(wave * 16 + l15) * 392 + kt * 32 + quad * 8]);
#pragma unroll
  for (int nt = 0; nt < 6; ++nt) {
    f32x4 acc = {0.f, 0.f, 0.f, 0.f};
#pragma unroll
    for (int kt = 0; kt < 12; ++kt) {
      half8 bf = *(const half8*)(fc2w + (size_t)(nt * 16 + l15) * 384 + kt * 32 + quad * 8);
      acc = MFMA(a2[kt], bf, acc);
    }
    int col = nt * 16 + l15;
    float bias = fc2b[col];
#pragma unroll
    for (int r = 0; r < 4; ++r) {
      int row = rowbase + wave * 16 + quad * 4 + r;
      out[(size_t)row * 96 + col] += acc[r] + bias;
    }
  }
}

extern "C" void kernel_launch(void* const* d_in, const int* in_sizes, int n_in,
                              void* d_out, int out_size, void* d_ws, size_t ws_size,
                              hipStream_t stream) {
  const float* x      = (const float*)d_in[0];
  const float* n1g    = (const float*)d_in[1];
  const float* n1b    = (const float*)d_in[2];
  const float* qkv_w  = (const float*)d_in[3];
  const float* qkv_b  = (const float*)d_in[4];
  const float* rtbl   = (const float*)d_in[5];
  const float* proj_w = (const float*)d_in[6];
  const float* proj_b = (const float*)d_in[7];
  const float* n2g    = (const float*)d_in[8];
  const float* n2b    = (const float*)d_in[9];
  const float* fc1_w  = (const float*)d_in[10];
  const float* fc1_b  = (const float*)d_in[11];
  const float* fc2_w  = (const float*)d_in[12];
  const float* fc2_b  = (const float*)d_in[13];
  float* out = (float*)d_out;
  char* ws = (char*)d_ws;

  if (ws_size < WS_NEEDED) return;  // fail visibly (poisoned d_out) rather than corrupt

  half_t* wbuf  = (half_t*)(ws + OFF_W);
  half_t* slotA = (half_t*)(ws + OFF_A);  // hwin -> attnout -> xnorm
  half_t* qkv16 = (half_t*)(ws + OFF_B);

  k_convert<<<432, 256, 0, stream>>>(qkv_w, proj_w, fc1_w, fc2_w, wbuf);
  k_ln1<<<1024, 256, 0, stream>>>(x, n1g, n1b, slotA);
  k_qkv<<<dim3(1024, 3), 256, 0, stream>>>(slotA, wbuf /*qkv_w16*/, qkv_b, qkv16);
  k_attn<<<16384, 64, 0, stream>>>(qkv16, rtbl, slotA /*attnout*/);
  k_proj<<<1024, 256, 0, stream>>>(slotA, wbuf + 27648 /*proj_w16*/, proj_b, x, out);
  k_ln2<<<1024, 256, 0, stream>>>(out, n2g, n2b, slotA /*xnorm*/);
  k_mlp<<<4096, 256, 0, stream>>>(slotA, wbuf + 36864 /*fc1_w16*/, fc1_b,
                                  wbuf + 73728 /*fc2_w16*/, fc2_b, out);
}

// Round 2
// 491.819 us; speedup vs baseline: 1.5838x; 1.5838x over previous
//
#include <hip/hip_runtime.h>
#include <hip/hip_fp16.h>
#include <math.h>

typedef _Float16 half_t;
typedef _Float16 half8 __attribute__((ext_vector_type(8)));
typedef _Float16 half4 __attribute__((ext_vector_type(4)));
typedef float f32x4 __attribute__((ext_vector_type(4)));

#define MFMA(a, b, c) __builtin_amdgcn_mfma_f32_16x16x32_f16((a), (b), (c), 0, 0, 0)

static constexpr float kScale = 0.2041241452319315f;  // 24^-0.5
static constexpr int QSTR = 200;  // qbuf row stride (halves): 400 B, 16B-mult, uniform banks
static constexpr int VTS  = 72;   // vT row stride (halves): 144 B
static constexpr int PS   = 72;   // pbuf row stride (halves)

// ---------------------------------------------------------------- weights -> fp16
__global__ __launch_bounds__(256) void k_convert(const float* __restrict__ qkv_w,
                                                 const float* __restrict__ proj_w,
                                                 const float* __restrict__ fc1_w,
                                                 const float* __restrict__ fc2_w,
                                                 half_t* __restrict__ wbuf) {
  int i = blockIdx.x * 256 + threadIdx.x;  // grid covers exactly 110592
  if (i < 27648)       wbuf[i] = (half_t)qkv_w[i];
  else if (i < 36864)  wbuf[i] = (half_t)proj_w[i - 27648];
  else if (i < 73728)  wbuf[i] = (half_t)fc1_w[i - 36864];
  else                 wbuf[i] = (half_t)fc2_w[i - 73728];
}

// ===== fused: LN1 + shift/window + QKV(MFMA) + attention(MFMA) + proj(MFMA) + residual
// block = 1 window (64 tokens), 256 threads (4 waves); wave==head during attention.
__global__ __launch_bounds__(256, 2) void k_attn_fused(
    const float* __restrict__ x, const float* __restrict__ n1g, const float* __restrict__ n1b,
    const half_t* __restrict__ qkvw, const float* __restrict__ qkv_b,
    const float* __restrict__ bias_table, const half_t* __restrict__ projw,
    const float* __restrict__ proj_b, float* __restrict__ out) {
  // manual layout in one block so vT over-reads (c in 24..31, garbage, discarded) stay in-bounds
  __shared__ __attribute__((aligned(16))) unsigned char smem[61760];
  half_t* qbuf = (half_t*)smem;                 // 64 x 200 halves: cols 0..95 Q->O, 96..191 K
  half_t* vT   = (half_t*)(smem + 25600);       // 4 heads x 24 x 72 (V transposed)
  half_t* pbuf = (half_t*)(smem + 39424);       // 4 heads x 32 x 72 (P, M-split)
  float*  tblf = (float*)(smem + 57856);        // 4 x 228
  int*    regb = (int*)(smem + 61504);          // 64 region ids

  int tid = threadIdx.x;
  int wave = tid >> 6, lane = tid & 63;
  int l15 = lane & 15, quad = lane >> 4;
  int blk = blockIdx.x;                          // bb*64 + wh*8 + ww
  int bb = blk >> 6, wh = (blk >> 3) & 7, ww = blk & 7;

  // stage rel-bias table (per-head rows) + region LUT for the shift mask
  for (int i = tid; i < 900; i += 256) tblf[(i & 3) * 228 + (i >> 2)] = bias_table[i];
  if (tid < 64) {
    int ih = tid >> 3, iw = tid & 7;
    int rr = wh * 8 + ih, cc = ww * 8 + iw;
    regb[tid] = ((rr < 56) ? 0 : ((rr < 60) ? 1 : 2)) * 3 + ((cc < 56) ? 0 : ((cc < 60) ? 1 : 2));
  }

  // ---- LN1 in registers (redundant per wave); builds A-frags for QKV GEMM
  half8 af[4][3];
  {
    float gg[24], bv[24];
#pragma unroll
    for (int kt = 0; kt < 3; ++kt) {
      int c0 = kt * 32 + quad * 8;
      float4 g0 = *(const float4*)(n1g + c0);
      float4 g1 = *(const float4*)(n1g + c0 + 4);
      float4 b0 = *(const float4*)(n1b + c0);
      float4 b1 = *(const float4*)(n1b + c0 + 4);
      gg[kt*8+0]=g0.x; gg[kt*8+1]=g0.y; gg[kt*8+2]=g0.z; gg[kt*8+3]=g0.w;
      gg[kt*8+4]=g1.x; gg[kt*8+5]=g1.y; gg[kt*8+6]=g1.z; gg[kt*8+7]=g1.w;
      bv[kt*8+0]=b0.x; bv[kt*8+1]=b0.y; bv[kt*8+2]=b0.z; bv[kt*8+3]=b0.w;
      bv[kt*8+4]=b1.x; bv[kt*8+5]=b1.y; bv[kt*8+6]=b1.z; bv[kt*8+7]=b1.w;
    }
#pragma unroll
    for (int g = 0; g < 4; ++g) {
      int tok = g * 16 + l15;
      int sr = (wh * 8 + (tok >> 3) + 4) & 63;
      int sc = (ww * 8 + (tok & 7) + 4) & 63;
      const float* rp = x + ((size_t)bb * 4096 + sr * 64 + sc) * 96;
      float v[24];
      float s1 = 0.f, s2 = 0.f;
#pragma unroll
      for (int kt = 0; kt < 3; ++kt) {
        float4 a = *(const float4*)(rp + kt * 32 + quad * 8);
        float4 b = *(const float4*)(rp + kt * 32 + quad * 8 + 4);
        v[kt*8+0]=a.x; v[kt*8+1]=a.y; v[kt*8+2]=a.z; v[kt*8+3]=a.w;
        v[kt*8+4]=b.x; v[kt*8+5]=b.y; v[kt*8+6]=b.z; v[kt*8+7]=b.w;
      }
#pragma unroll
      for (int c = 0; c < 24; ++c) { s1 += v[c]; s2 += v[c] * v[c]; }
      s1 += __shfl_xor(s1, 16); s1 += __shfl_xor(s1, 32);
      s2 += __shfl_xor(s2, 16); s2 += __shfl_xor(s2, 32);
      float mu = s1 * (1.f / 96.f);
      float inv = rsqrtf(fmaxf(s2 * (1.f / 96.f) - mu * mu, 0.f) + 1e-5f);
#pragma unroll
      for (int kt = 0; kt < 3; ++kt) {
        half8 h;
#pragma unroll
        for (int j = 0; j < 8; ++j)
          h[j] = (half_t)((v[kt*8+j] - mu) * inv * gg[kt*8+j] + bv[kt*8+j]);
        af[g][kt] = h;
      }
    }
  }

  // ---- QKV GEMM: 18 N-tiles round-robin over 4 waves
  for (int t = wave; t < 18; t += 4) {
    half8 bf[3];
#pragma unroll
    for (int kt = 0; kt < 3; ++kt)
      bf[kt] = *(const half8*)(qkvw + (size_t)(t * 16 + l15) * 96 + kt * 32 + quad * 8);
    f32x4 acc[4] = {{0,0,0,0},{0,0,0,0},{0,0,0,0},{0,0,0,0}};
#pragma unroll
    for (int kt = 0; kt < 3; ++kt)
#pragma unroll
      for (int g = 0; g < 4; ++g)
        acc[g] = MFMA(af[g][kt], bf[kt], acc[g]);
    int col = t * 16 + l15;
    float bias = qkv_b[col];
    if (t < 12) {
      float sc_ = (t < 6) ? kScale : 1.f;
#pragma unroll
      for (int g = 0; g < 4; ++g)
#pragma unroll
        for (int r = 0; r < 4; ++r)
          qbuf[(g * 16 + quad * 4 + r) * QSTR + col] = (half_t)((acc[g][r] + bias) * sc_);
    } else {
      int vc = col - 192;            // 0..95
      int hd = vc / 24, c = vc - hd * 24;
#pragma unroll
      for (int g = 0; g < 4; ++g)
#pragma unroll
        for (int r = 0; r < 4; ++r)
          vT[hd * 24 * VTS + c * VTS + g * 16 + quad * 4 + r] = (half_t)(acc[g][r] + bias);
    }
  }
  __syncthreads();

  // ---- attention (wave = head), all-MFMA
  {
    int head = wave;
    const half8 z8 = {};
    half8 qa[4], kb[4], vb[2][2];
#pragma unroll
    for (int g = 0; g < 4; ++g) {
      half8 t = *(const half8*)(&qbuf[(g * 16 + l15) * QSTR + head * 24 + quad * 8]);
      qa[g] = (quad < 3) ? t : z8;   // zero K-pad 24..31 (both sides zeroed -> no 0*NaN)
    }
#pragma unroll
    for (int nt = 0; nt < 4; ++nt) {
      half8 t = *(const half8*)(&qbuf[(nt * 16 + l15) * QSTR + 96 + head * 24 + quad * 8]);
      kb[nt] = (quad < 3) ? t : z8;
    }
#pragma unroll
    for (int nt = 0; nt < 2; ++nt)
#pragma unroll
      for (int kt = 0; kt < 2; ++kt)
        vb[nt][kt] = *(const half8*)(&vT[head * 24 * VTS + (nt * 16 + l15) * VTS + kt * 32 + quad * 8]);

    float s[4][4][4];  // [g][nt][r]; lane holds S[g*16+quad*4+r][nt*16+l15]
#pragma unroll
    for (int g = 0; g < 4; ++g)
#pragma unroll
      for (int nt = 0; nt < 4; ++nt) {
        f32x4 a = {0, 0, 0, 0};
        a = MFMA(qa[g], kb[nt], a);
#pragma unroll
        for (int r = 0; r < 4; ++r) s[g][nt][r] = a[r];
      }

    int rj[4], jh_[4], jw_[4];
#pragma unroll
    for (int nt = 0; nt < 4; ++nt) {
      int j = nt * 16 + l15;
      rj[nt] = regb[j]; jh_[nt] = j >> 3; jw_[nt] = j & 7;
    }
    float inv_[4][4];
#pragma unroll
    for (int g = 0; g < 4; ++g)
#pragma unroll
      for (int r = 0; r < 4; ++r) {
        int i = g * 16 + quad * 4 + r;
        int ih = i >> 3, iw = i & 7;
        int ri = regb[i];
#pragma unroll
        for (int nt = 0; nt < 4; ++nt) {
          float val = s[g][nt][r] + tblf[head * 228 + (ih - jh_[nt] + 7) * 15 + (iw - jw_[nt] + 7)];
          if (ri != rj[nt]) val -= 100.f;
          s[g][nt][r] = val;
        }
        float mx = fmaxf(fmaxf(s[g][0][r], s[g][1][r]), fmaxf(s[g][2][r], s[g][3][r]));
        mx = fmaxf(mx, __shfl_xor(mx, 1));
        mx = fmaxf(mx, __shfl_xor(mx, 2));
        mx = fmaxf(mx, __shfl_xor(mx, 4));
        mx = fmaxf(mx, __shfl_xor(mx, 8));
        float sum = 0.f;
#pragma unroll
        for (int nt = 0; nt < 4; ++nt) {
          float e = __expf(s[g][nt][r] - mx);
          s[g][nt][r] = e;
          sum += e;
        }
        sum += __shfl_xor(sum, 1);
        sum += __shfl_xor(sum, 2);
        sum += __shfl_xor(sum, 4);
        sum += __shfl_xor(sum, 8);
        inv_[g][r] = 1.f / sum;
      }

    // PV in two M-halves through wave-private P buffer (C-layout -> A-layout)
    half_t* pb = pbuf + head * 32 * PS;
#pragma unroll
    for (int hv = 0; hv < 2; ++hv) {
#pragma unroll
      for (int g2 = 0; g2 < 2; ++g2) {
        int g = hv * 2 + g2;
#pragma unroll
        for (int nt = 0; nt < 4; ++nt)
#pragma unroll
          for (int r = 0; r < 4; ++r)
            pb[(g2 * 16 + quad * 4 + r) * PS + nt * 16 + l15] = (half_t)s[g][nt][r];
      }
      f32x4 oacc[2][2] = {{{0,0,0,0},{0,0,0,0}},{{0,0,0,0},{0,0,0,0}}};
#pragma unroll
      for (int g2 = 0; g2 < 2; ++g2) {
        half8 pa[2];
#pragma unroll
        for (int kt = 0; kt < 2; ++kt)
          pa[kt] = *(const half8*)(&pb[(g2 * 16 + l15) * PS + kt * 32 + quad * 8]);
#pragma unroll
        for (int nt = 0; nt < 2; ++nt)
#pragma unroll
          for (int kt = 0; kt < 2; ++kt)
            oacc[g2][nt] = MFMA(pa[kt], vb[nt][kt], oacc[g2][nt]);
      }
#pragma unroll
      for (int g2 = 0; g2 < 2; ++g2)
#pragma unroll
        for (int nt = 0; nt < 2; ++nt)
#pragma unroll
          for (int r = 0; r < 4; ++r) {
            int c = nt * 16 + l15;
            if (c < 24)   // cols 24..31 are K-pad garbage, discard
              qbuf[(hv * 32 + g2 * 16 + quad * 4 + r) * QSTR + head * 24 + c] =
                  (half_t)(oacc[g2][nt][r] * inv_[hv * 2 + g2][r]);
          }
    }
  }
  __syncthreads();

  // ---- proj GEMM + window-reverse/unshift + residual -> out
  {
    half8 pa2[4][3];
#pragma unroll
    for (int g = 0; g < 4; ++g)
#pragma unroll
      for (int kt = 0; kt < 3; ++kt)
        pa2[g][kt] = *(const half8*)(&qbuf[(g * 16 + l15) * QSTR + kt * 32 + quad * 8]);
    for (int t = wave; t < 6; t += 4) {
      half8 bf[3];
#pragma unroll
      for (int kt = 0; kt < 3; ++kt)
        bf[kt] = *(const half8*)(projw + (size_t)(t * 16 + l15) * 96 + kt * 32 + quad * 8);
      f32x4 acc[4] = {{0,0,0,0},{0,0,0,0},{0,0,0,0},{0,0,0,0}};
#pragma unroll
      for (int kt = 0; kt < 3; ++kt)
#pragma unroll
        for (int g = 0; g < 4; ++g)
          acc[g] = MFMA(pa2[g][kt], bf[kt], acc[g]);
      int col = t * 16 + l15;
      float bias = proj_b[col];
#pragma unroll
      for (int g = 0; g < 4; ++g)
#pragma unroll
        for (int r = 0; r < 4; ++r) {
          int tok = g * 16 + quad * 4 + r;
          int sr = (wh * 8 + (tok >> 3) + 4) & 63;
          int sc = (ww * 8 + (tok & 7) + 4) & 63;
          size_t fidx = ((size_t)bb * 4096 + sr * 64 + sc) * 96 + col;
          out[fidx] = x[fidx] + acc[g][r] + bias;
        }
    }
  }
}

// ===== fused MLP: LN2 + fc1 + GELU(exact) + fc2 + residual RMW. 512 threads, 64 rows/block.
__global__ __launch_bounds__(512, 4) void k_mlp(
    const float* __restrict__ n2g, const float* __restrict__ n2b,
    const half_t* __restrict__ fc1w, const float* __restrict__ fc1b,
    const half_t* __restrict__ fc2w, const float* __restrict__ fc2b,
    float* __restrict__ out) {
  __shared__ __attribute__((aligned(16))) half_t xn[64 * 104];   // 13312 B
  __shared__ __attribute__((aligned(16))) half_t h1[64 * 392];   // 50176 B
  int tid = threadIdx.x;
  int wave = tid >> 6, lane = tid & 63;
  int l15 = lane & 15, quad = lane >> 4;
  int rowbase = blockIdx.x * 64;

  // ---- LN2: wave w -> rows 8w..8w+7; lane: row=8w+(lane>>3), cols (lane&7)*12..+11
  {
    int r = wave * 8 + (lane >> 3);
    int ch = lane & 7;
    const float* rp = out + (size_t)(rowbase + r) * 96 + ch * 12;
    float v[12];
    float4 a = *(const float4*)rp;
    float4 b = *(const float4*)(rp + 4);
    float4 c = *(const float4*)(rp + 8);
    v[0]=a.x; v[1]=a.y; v[2]=a.z; v[3]=a.w;
    v[4]=b.x; v[5]=b.y; v[6]=b.z; v[7]=b.w;
    v[8]=c.x; v[9]=c.y; v[10]=c.z; v[11]=c.w;
    float s1 = 0.f, s2 = 0.f;
#pragma unroll
    for (int j = 0; j < 12; ++j) { s1 += v[j]; s2 += v[j] * v[j]; }
    s1 += __shfl_xor(s1, 1); s1 += __shfl_xor(s1, 2); s1 += __shfl_xor(s1, 4);
    s2 += __shfl_xor(s2, 1); s2 += __shfl_xor(s2, 2); s2 += __shfl_xor(s2, 4);
    float mu = s1 * (1.f / 96.f);
    float inv = rsqrtf(fmaxf(s2 * (1.f / 96.f) - mu * mu, 0.f) + 1e-5f);
    float4 g0 = *(const float4*)(n2g + ch * 12);
    float4 g1 = *(const float4*)(n2g + ch * 12 + 4);
    float4 g2 = *(const float4*)(n2g + ch * 12 + 8);
    float4 b0 = *(const float4*)(n2b + ch * 12);
    float4 b1 = *(const float4*)(n2b + ch * 12 + 4);
    float4 b2 = *(const float4*)(n2b + ch * 12 + 8);
    float gv[12] = {g0.x,g0.y,g0.z,g0.w,g1.x,g1.y,g1.z,g1.w,g2.x,g2.y,g2.z,g2.w};
    float bb[12] = {b0.x,b0.y,b0.z,b0.w,b1.x,b1.y,b1.z,b1.w,b2.x,b2.y,b2.z,b2.w};
    half_t* op = xn + r * 104 + ch * 12;
    half4 h0, h1v, h2v;
#pragma unroll
    for (int j = 0; j < 4; ++j) {
      h0[j]  = (half_t)((v[j]     - mu) * inv * gv[j]     + bb[j]);
      h1v[j] = (half_t)((v[j + 4] - mu) * inv * gv[j + 4] + bb[j + 4]);
      h2v[j] = (half_t)((v[j + 8] - mu) * inv * gv[j + 8] + bb[j + 8]);
    }
    *(half4*)(op) = h0; *(half4*)(op + 4) = h1v; *(half4*)(op + 8) = h2v;
  }
  __syncthreads();

  // ---- fc1 + GELU: wave w -> N-tiles 3w..3w+2 (cols 48w..48w+47)
  {
    half8 af[4][3];
#pragma unroll
    for (int g = 0; g < 4; ++g)
#pragma unroll
      for (int kt = 0; kt < 3; ++kt)
        af[g][kt] = *(const half8*)(&xn[(g * 16 + l15) * 104 + kt * 32 + quad * 8]);
#pragma unroll
    for (int i = 0; i < 3; ++i) {
      int t = wave * 3 + i;
      int n0 = t * 16 + l15;
      half8 bf[3];
#pragma unroll
      for (int kt = 0; kt < 3; ++kt)
        bf[kt] = *(const half8*)(fc1w + (size_t)n0 * 96 + kt * 32 + quad * 8);
      f32x4 acc[4] = {{0,0,0,0},{0,0,0,0},{0,0,0,0},{0,0,0,0}};
#pragma unroll
      for (int kt = 0; kt < 3; ++kt)
#pragma unroll
        for (int g = 0; g < 4; ++g)
          acc[g] = MFMA(af[g][kt], bf[kt], acc[g]);
      float bias = fc1b[n0];
#pragma unroll
      for (int g = 0; g < 4; ++g)
#pragma unroll
        for (int r = 0; r < 4; ++r) {
          float vv = acc[g][r] + bias;
          vv = 0.5f * vv * (1.f + erff(vv * 0.70710678118f));
          h1[(g * 16 + quad * 4 + r) * 392 + n0] = (half_t)vv;
        }
    }
  }
  __syncthreads();

  // ---- fc2 + residual: wave -> (row-tile = wave>>1, col-half = wave&1)
  {
    int rt = wave >> 1, chh = wave & 1;
    half8 a2[12];
#pragma unroll
    for (int kt = 0; kt < 12; ++kt)
      a2[kt] = *(const half8*)(&h1[(rt * 16 + l15) * 392 + kt * 32 + quad * 8]);
#pragma unroll
    for (int i = 0; i < 3; ++i) {
      int t = chh * 3 + i;
      f32x4 acc = {0, 0, 0, 0};
#pragma unroll
      for (int kt = 0; kt < 12; ++kt) {
        half8 bf = *(const half8*)(fc2w + (size_t)(t * 16 + l15) * 384 + kt * 32 + quad * 8);
        acc = MFMA(a2[kt], bf, acc);
      }
      int col = t * 16 + l15;
      float bias = fc2b[col];
#pragma unroll
      for (int r = 0; r < 4; ++r) {
        size_t o = (size_t)(rowbase + rt * 16 + quad * 4 + r) * 96 + col;
        out[o] += acc[r] + bias;
      }
    }
  }
}

extern "C" void kernel_launch(void* const* d_in, const int* in_sizes, int n_in,
                              void* d_out, int out_size, void* d_ws, size_t ws_size,
                              hipStream_t stream) {
  const float* x      = (const float*)d_in[0];
  const float* n1g    = (const float*)d_in[1];
  const float* n1b    = (const float*)d_in[2];
  const float* qkv_w  = (const float*)d_in[3];
  const float* qkv_b  = (const float*)d_in[4];
  const float* rtbl   = (const float*)d_in[5];
  const float* proj_w = (const float*)d_in[6];
  const float* proj_b = (const float*)d_in[7];
  const float* n2g    = (const float*)d_in[8];
  const float* n2b    = (const float*)d_in[9];
  const float* fc1_w  = (const float*)d_in[10];
  const float* fc1_b  = (const float*)d_in[11];
  const float* fc2_w  = (const float*)d_in[12];
  const float* fc2_b  = (const float*)d_in[13];
  float* out = (float*)d_out;

  if (ws_size < 221184) return;
  half_t* wbuf = (half_t*)d_ws;

  k_convert<<<432, 256, 0, stream>>>(qkv_w, proj_w, fc1_w, fc2_w, wbuf);
  k_attn_fused<<<4096, 256, 0, stream>>>(x, n1g, n1b, wbuf, qkv_b, rtbl,
                                         wbuf + 27648, proj_b, out);
  k_mlp<<<4096, 512, 0, stream>>>(n2g, n2b, wbuf + 36864, fc1_b,
                                  wbuf + 73728, fc2_b, out);
}

// Round 3
// 473.915 us; speedup vs baseline: 1.6437x; 1.0378x over previous
//
#include <hip/hip_runtime.h>
#include <hip/hip_fp16.h>
#include <math.h>

typedef _Float16 half_t;
typedef _Float16 half8 __attribute__((ext_vector_type(8)));
typedef float f32x4 __attribute__((ext_vector_type(4)));

#define MFMA(a, b, c) __builtin_amdgcn_mfma_f32_16x16x32_f16((a), (b), (c), 0, 0, 0)

static constexpr float kScale = 0.2041241452319315f;  // 24^-0.5
static constexpr int RS   = 104;  // resid / hn / xn row stride (halves)
static constexpr int QSTR = 200;  // qbuf row stride
static constexpr int VTS  = 72;   // vT row stride
static constexpr int PS   = 72;   // pbuf row stride
static constexpr int H1S  = 392;  // h1 row stride

// ---------------------------------------------------------------- weights -> fp16
__global__ __launch_bounds__(256) void k_convert(const float* __restrict__ qkv_w,
                                                 const float* __restrict__ proj_w,
                                                 const float* __restrict__ fc1_w,
                                                 const float* __restrict__ fc2_w,
                                                 half_t* __restrict__ wbuf) {
  int i = blockIdx.x * 256 + threadIdx.x;  // grid covers exactly 110592
  if (i < 27648)       wbuf[i] = (half_t)qkv_w[i];
  else if (i < 36864)  wbuf[i] = (half_t)proj_w[i - 27648];
  else if (i < 73728)  wbuf[i] = (half_t)fc1_w[i - 36864];
  else                 wbuf[i] = (half_t)fc2_w[i - 73728];
}

// ===== whole Swin block fused, one 64-token window per 256-thread block =====
// P0 LN1 -> P1 QKV -> P2 attn (wave==head) -> P3 proj+residual -> P4 LN2
// -> P5 fc1+GELU -> P6 fc2+residual -> single out write.
__global__ __launch_bounds__(256, 2) void k_swin(
    const float* __restrict__ x,
    const float* __restrict__ n1g, const float* __restrict__ n1b,
    const half_t* __restrict__ qkvw, const float* __restrict__ qkv_b,
    const float* __restrict__ tbl_g, const half_t* __restrict__ projw,
    const float* __restrict__ proj_b,
    const float* __restrict__ n2g, const float* __restrict__ n2b,
    const half_t* __restrict__ fc1w, const float* __restrict__ fc1b,
    const half_t* __restrict__ fc2w, const float* __restrict__ fc2b,
    float* __restrict__ out) {
  // 13312 (persistent resid) + 63488 (phase union) = 76800 B -> 2 blocks/CU
  __shared__ __attribute__((aligned(16))) unsigned char smem[76800];
  half_t* resid = (half_t*)smem;               // 64 x RS f16: x rows -> residual r
  unsigned char* U = smem + 13312;
  half_t* qbuf = (half_t*)U;                   // 64 x 200: cols 0..95 Q->O, 96..191 K
  half_t* vT   = (half_t*)(U + 25600);         // 4 x 24 x VTS
  half_t* pbuf = (half_t*)(U + 39424);         // 4 x 32 x PS (P2); aliases hn (P0-P1)
  half_t* hn   = (half_t*)(U + 39424);         // 64 x RS normalized LN1 out
  float*  tblf = (float*)(U + 57856);          // 4 x 228
  int*    regb = (int*)(U + 61504);            // 64 region ids
  half_t* h1   = (half_t*)U;                   // 64 x H1S (P5+, aliases qbuf/vT/pbuf)
  half_t* xn   = (half_t*)(U + 50176);         // 64 x RS (P4+, aliases pbuf tail/tbl)

  int tid = threadIdx.x;
  int wave = tid >> 6, lane = tid & 63;
  int l15 = lane & 15, quad = lane >> 4;
  int blk = blockIdx.x;                        // bb*64 + wh*8 + ww
  int bb = blk >> 6, wh = (blk >> 3) & 7, ww = blk & 7;

  // stage rel-bias table (per-head rows) + region LUT for the shift mask
  for (int i = tid; i < 900; i += 256) tblf[(i & 3) * 228 + (i >> 2)] = tbl_g[i];
  if (tid < 64) {
    int ih = tid >> 3, iw = tid & 7;
    int rr = wh * 8 + ih, cc = ww * 8 + iw;
    regb[tid] = ((rr < 56) ? 0 : ((rr < 60) ? 1 : 2)) * 3 + ((cc < 56) ? 0 : ((cc < 60) ? 1 : 2));
  }

  // ---- P0: LN1, each wave owns 16 rows; saves x (f16) to resid, LN1 out to hn
  {
    int tok = wave * 16 + l15;
    float gg[24], bv[24];
#pragma unroll
    for (int kt = 0; kt < 3; ++kt) {
      int c0 = kt * 32 + quad * 8;
      float4 g0 = *(const float4*)(n1g + c0);
      float4 g1 = *(const float4*)(n1g + c0 + 4);
      float4 b0 = *(const float4*)(n1b + c0);
      float4 b1 = *(const float4*)(n1b + c0 + 4);
      gg[kt*8+0]=g0.x; gg[kt*8+1]=g0.y; gg[kt*8+2]=g0.z; gg[kt*8+3]=g0.w;
      gg[kt*8+4]=g1.x; gg[kt*8+5]=g1.y; gg[kt*8+6]=g1.z; gg[kt*8+7]=g1.w;
      bv[kt*8+0]=b0.x; bv[kt*8+1]=b0.y; bv[kt*8+2]=b0.z; bv[kt*8+3]=b0.w;
      bv[kt*8+4]=b1.x; bv[kt*8+5]=b1.y; bv[kt*8+6]=b1.z; bv[kt*8+7]=b1.w;
    }
    int sr = (wh * 8 + (tok >> 3) + 4) & 63;
    int sc = (ww * 8 + (tok & 7) + 4) & 63;
    const float* rp = x + ((size_t)bb * 4096 + sr * 64 + sc) * 96;
    float v[24];
    float s1 = 0.f, s2 = 0.f;
#pragma unroll
    for (int kt = 0; kt < 3; ++kt) {
      float4 a = *(const float4*)(rp + kt * 32 + quad * 8);
      float4 b = *(const float4*)(rp + kt * 32 + quad * 8 + 4);
      v[kt*8+0]=a.x; v[kt*8+1]=a.y; v[kt*8+2]=a.z; v[kt*8+3]=a.w;
      v[kt*8+4]=b.x; v[kt*8+5]=b.y; v[kt*8+6]=b.z; v[kt*8+7]=b.w;
    }
#pragma unroll
    for (int c = 0; c < 24; ++c) { s1 += v[c]; s2 += v[c] * v[c]; }
    s1 += __shfl_xor(s1, 16); s1 += __shfl_xor(s1, 32);
    s2 += __shfl_xor(s2, 16); s2 += __shfl_xor(s2, 32);
    float mu = s1 * (1.f / 96.f);
    float inv = rsqrtf(fmaxf(s2 * (1.f / 96.f) - mu * mu, 0.f) + 1e-5f);
#pragma unroll
    for (int kt = 0; kt < 3; ++kt) {
      half8 hh, rr;
#pragma unroll
      for (int j = 0; j < 8; ++j) {
        float val = v[kt*8+j];
        rr[j] = (half_t)val;
        hh[j] = (half_t)((val - mu) * inv * gg[kt*8+j] + bv[kt*8+j]);
      }
      *(half8*)(&resid[tok * RS + kt * 32 + quad * 8]) = rr;
      *(half8*)(&hn[tok * RS + kt * 32 + quad * 8]) = hh;
    }
  }
  __syncthreads();

  // ---- P1: QKV GEMM (18 N-tiles round-robin over 4 waves) -> qbuf / vT
  {
    half8 af[4][3];
#pragma unroll
    for (int g = 0; g < 4; ++g)
#pragma unroll
      for (int kt = 0; kt < 3; ++kt)
        af[g][kt] = *(const half8*)(&hn[(g * 16 + l15) * RS + kt * 32 + quad * 8]);
    for (int t = wave; t < 18; t += 4) {
      half8 bf[3];
#pragma unroll
      for (int kt = 0; kt < 3; ++kt)
        bf[kt] = *(const half8*)(qkvw + (size_t)(t * 16 + l15) * 96 + kt * 32 + quad * 8);
      f32x4 acc[4] = {{0,0,0,0},{0,0,0,0},{0,0,0,0},{0,0,0,0}};
#pragma unroll
      for (int kt = 0; kt < 3; ++kt)
#pragma unroll
        for (int g = 0; g < 4; ++g)
          acc[g] = MFMA(af[g][kt], bf[kt], acc[g]);
      int col = t * 16 + l15;
      float bias = qkv_b[col];
      if (t < 12) {
        float sc_ = (t < 6) ? kScale : 1.f;
#pragma unroll
        for (int g = 0; g < 4; ++g)
#pragma unroll
          for (int r = 0; r < 4; ++r)
            qbuf[(g * 16 + quad * 4 + r) * QSTR + col] = (half_t)((acc[g][r] + bias) * sc_);
      } else {
        int vc = col - 192;
        int hd = vc / 24, c = vc - hd * 24;
#pragma unroll
        for (int g = 0; g < 4; ++g)
#pragma unroll
          for (int r = 0; r < 4; ++r)
            vT[hd * 24 * VTS + c * VTS + g * 16 + quad * 4 + r] = (half_t)(acc[g][r] + bias);
      }
    }
  }
  __syncthreads();

  // ---- P2: attention (wave = head), all-MFMA; O held in regs across a barrier
  f32x4 oacc[2][2][2];
  float inv_[4][4];
  {
    int head = wave;
    const half8 z8 = {};
    half8 qa[4], kb[4], vb[2][2];
#pragma unroll
    for (int g = 0; g < 4; ++g) {
      half8 t = *(const half8*)(&qbuf[(g * 16 + l15) * QSTR + head * 24 + quad * 8]);
      qa[g] = (quad < 3) ? t : z8;   // zero K-pad 24..31 on both operands
    }
#pragma unroll
    for (int nt = 0; nt < 4; ++nt) {
      half8 t = *(const half8*)(&qbuf[(nt * 16 + l15) * QSTR + 96 + head * 24 + quad * 8]);
      kb[nt] = (quad < 3) ? t : z8;
    }
#pragma unroll
    for (int nt = 0; nt < 2; ++nt)
#pragma unroll
      for (int kt = 0; kt < 2; ++kt)
        vb[nt][kt] = *(const half8*)(&vT[head * 24 * VTS + (nt * 16 + l15) * VTS + kt * 32 + quad * 8]);

    float s[4][4][4];  // [g][nt][r]
#pragma unroll
    for (int g = 0; g < 4; ++g)
#pragma unroll
      for (int nt = 0; nt < 4; ++nt) {
        f32x4 a = {0, 0, 0, 0};
        a = MFMA(qa[g], kb[nt], a);
#pragma unroll
        for (int r = 0; r < 4; ++r) s[g][nt][r] = a[r];
      }

    int rj[4], jh_[4], jw_[4];
#pragma unroll
    for (int nt = 0; nt < 4; ++nt) {
      int j = nt * 16 + l15;
      rj[nt] = regb[j]; jh_[nt] = j >> 3; jw_[nt] = j & 7;
    }
#pragma unroll
    for (int g = 0; g < 4; ++g)
#pragma unroll
      for (int r = 0; r < 4; ++r) {
        int i = g * 16 + quad * 4 + r;
        int ih = i >> 3, iw = i & 7;
        int ri = regb[i];
#pragma unroll
        for (int nt = 0; nt < 4; ++nt) {
          float val = s[g][nt][r] + tblf[head * 228 + (ih - jh_[nt] + 7) * 15 + (iw - jw_[nt] + 7)];
          if (ri != rj[nt]) val -= 100.f;
          s[g][nt][r] = val;
        }
        float mx = fmaxf(fmaxf(s[g][0][r], s[g][1][r]), fmaxf(s[g][2][r], s[g][3][r]));
        mx = fmaxf(mx, __shfl_xor(mx, 1));
        mx = fmaxf(mx, __shfl_xor(mx, 2));
        mx = fmaxf(mx, __shfl_xor(mx, 4));
        mx = fmaxf(mx, __shfl_xor(mx, 8));
        float sum = 0.f;
#pragma unroll
        for (int nt = 0; nt < 4; ++nt) {
          float e = __expf(s[g][nt][r] - mx);
          s[g][nt][r] = e;
          sum += e;
        }
        sum += __shfl_xor(sum, 1);
        sum += __shfl_xor(sum, 2);
        sum += __shfl_xor(sum, 4);
        sum += __shfl_xor(sum, 8);
        inv_[g][r] = 1.f / sum;
      }

    half_t* pb = pbuf + head * 32 * PS;  // wave-private
#pragma unroll
    for (int hv = 0; hv < 2; ++hv) {
#pragma unroll
      for (int g2 = 0; g2 < 2; ++g2) {
        int g = hv * 2 + g2;
#pragma unroll
        for (int nt = 0; nt < 4; ++nt)
#pragma unroll
          for (int r = 0; r < 4; ++r)
            pb[(g2 * 16 + quad * 4 + r) * PS + nt * 16 + l15] = (half_t)s[g][nt][r];
      }
#pragma unroll
      for (int g2 = 0; g2 < 2; ++g2) {
        half8 pa[2];
#pragma unroll
        for (int kt = 0; kt < 2; ++kt)
          pa[kt] = *(const half8*)(&pb[(g2 * 16 + l15) * PS + kt * 32 + quad * 8]);
#pragma unroll
        for (int nt = 0; nt < 2; ++nt) {
          f32x4 a = {0, 0, 0, 0};
#pragma unroll
          for (int kt = 0; kt < 2; ++kt) a = MFMA(pa[kt], vb[nt][kt], a);
          oacc[hv][g2][nt] = a;
        }
      }
    }
  }
  __syncthreads();  // all waves' Q/K reads complete before O overwrites qbuf
  {
    int head = wave;
#pragma unroll
    for (int hv = 0; hv < 2; ++hv)
#pragma unroll
      for (int g2 = 0; g2 < 2; ++g2)
#pragma unroll
        for (int nt = 0; nt < 2; ++nt)
#pragma unroll
          for (int r = 0; r < 4; ++r) {
            int c = nt * 16 + l15;
            if (c < 24)  // cols 24..31 are K-pad garbage
              qbuf[(hv * 32 + g2 * 16 + quad * 4 + r) * QSTR + head * 24 + c] =
                  (half_t)(oacc[hv][g2][nt][r] * inv_[hv * 2 + g2][r]);
          }
  }
  __syncthreads();

  // ---- P3: proj + residual (resid := x + attn_out, f16, in LDS)
  {
    half8 pa2[4][3];
#pragma unroll
    for (int g = 0; g < 4; ++g)
#pragma unroll
      for (int kt = 0; kt < 3; ++kt)
        pa2[g][kt] = *(const half8*)(&qbuf[(g * 16 + l15) * QSTR + kt * 32 + quad * 8]);
    for (int t = wave; t < 6; t += 4) {
      half8 bf[3];
#pragma unroll
      for (int kt = 0; kt < 3; ++kt)
        bf[kt] = *(const half8*)(projw + (size_t)(t * 16 + l15) * 96 + kt * 32 + quad * 8);
      f32x4 acc[4] = {{0,0,0,0},{0,0,0,0},{0,0,0,0},{0,0,0,0}};
#pragma unroll
      for (int kt = 0; kt < 3; ++kt)
#pragma unroll
        for (int g = 0; g < 4; ++g)
          acc[g] = MFMA(pa2[g][kt], bf[kt], acc[g]);
      int col = t * 16 + l15;
      float bias = proj_b[col];
#pragma unroll
      for (int g = 0; g < 4; ++g)
#pragma unroll
        for (int r = 0; r < 4; ++r) {
          int row = g * 16 + quad * 4 + r;
          float rv = (float)resid[row * RS + col] + acc[g][r] + bias;
          resid[row * RS + col] = (half_t)rv;
        }
    }
  }
  __syncthreads();

  // ---- P4: LN2 from resid -> xn
  {
    int r4 = wave * 16 + (lane >> 2);
    int ch = lane & 3;  // 24-col chunk
    const half_t* rp = resid + r4 * RS + ch * 24;
    half8 w0 = *(const half8*)(rp);
    half8 w1 = *(const half8*)(rp + 8);
    half8 w2 = *(const half8*)(rp + 16);
    float v[24];
#pragma unroll
    for (int j = 0; j < 8; ++j) {
      v[j] = (float)w0[j]; v[j + 8] = (float)w1[j]; v[j + 16] = (float)w2[j];
    }
    float s1 = 0.f, s2 = 0.f;
#pragma unroll
    for (int j = 0; j < 24; ++j) { s1 += v[j]; s2 += v[j] * v[j]; }
    s1 += __shfl_xor(s1, 1); s1 += __shfl_xor(s1, 2);
    s2 += __shfl_xor(s2, 1); s2 += __shfl_xor(s2, 2);
    float mu = s1 * (1.f / 96.f);
    float inv = rsqrtf(fmaxf(s2 * (1.f / 96.f) - mu * mu, 0.f) + 1e-5f);
    float gv[24], bb2[24];
#pragma unroll
    for (int q = 0; q < 6; ++q) {
      float4 g4 = *(const float4*)(n2g + ch * 24 + q * 4);
      float4 b4 = *(const float4*)(n2b + ch * 24 + q * 4);
      gv[q*4+0]=g4.x; gv[q*4+1]=g4.y; gv[q*4+2]=g4.z; gv[q*4+3]=g4.w;
      bb2[q*4+0]=b4.x; bb2[q*4+1]=b4.y; bb2[q*4+2]=b4.z; bb2[q*4+3]=b4.w;
    }
    half_t* op = xn + r4 * RS + ch * 24;
#pragma unroll
    for (int q = 0; q < 3; ++q) {
      half8 h;
#pragma unroll
      for (int j = 0; j < 8; ++j)
        h[j] = (half_t)((v[q*8+j] - mu) * inv * gv[q*8+j] + bb2[q*8+j]);
      *(half8*)(op + q * 8) = h;
    }
  }
  __syncthreads();

  // ---- P5: fc1 + GELU(exact) -> h1
  {
    half8 a5[4][3];
#pragma unroll
    for (int g = 0; g < 4; ++g)
#pragma unroll
      for (int kt = 0; kt < 3; ++kt)
        a5[g][kt] = *(const half8*)(&xn[(g * 16 + l15) * RS + kt * 32 + quad * 8]);
    for (int t = wave; t < 24; t += 4) {
      int n0 = t * 16 + l15;
      half8 bf[3];
#pragma unroll
      for (int kt = 0; kt < 3; ++kt)
        bf[kt] = *(const half8*)(fc1w + (size_t)n0 * 96 + kt * 32 + quad * 8);
      f32x4 acc[4] = {{0,0,0,0},{0,0,0,0},{0,0,0,0},{0,0,0,0}};
#pragma unroll
      for (int kt = 0; kt < 3; ++kt)
#pragma unroll
        for (int g = 0; g < 4; ++g)
          acc[g] = MFMA(a5[g][kt], bf[kt], acc[g]);
      float bias = fc1b[n0];
#pragma unroll
      for (int g = 0; g < 4; ++g)
#pragma unroll
        for (int r = 0; r < 4; ++r) {
          float vv = acc[g][r] + bias;
          vv = 0.5f * vv * (1.f + erff(vv * 0.70710678118f));
          h1[(g * 16 + quad * 4 + r) * H1S + n0] = (half_t)vv;
        }
    }
  }
  __syncthreads();

  // ---- P6: fc2 + residual -> single out write
  {
    int rt = wave;
    half8 a2[12];
#pragma unroll
    for (int kt = 0; kt < 12; ++kt)
      a2[kt] = *(const half8*)(&h1[(rt * 16 + l15) * H1S + kt * 32 + quad * 8]);
#pragma unroll
    for (int t = 0; t < 6; ++t) {
      f32x4 acc = {0, 0, 0, 0};
#pragma unroll
      for (int kt = 0; kt < 12; ++kt) {
        half8 bf = *(const half8*)(fc2w + (size_t)(t * 16 + l15) * 384 + kt * 32 + quad * 8);
        acc = MFMA(a2[kt], bf, acc);
      }
      int col = t * 16 + l15;
      float bias = fc2b[col];
#pragma unroll
      for (int r = 0; r < 4; ++r) {
        int tok = rt * 16 + quad * 4 + r;
        int sr = (wh * 8 + (tok >> 3) + 4) & 63;
        int sc = (ww * 8 + (tok & 7) + 4) & 63;
        size_t fidx = ((size_t)bb * 4096 + sr * 64 + sc) * 96 + col;
        out[fidx] = (float)resid[tok * RS + col] + acc[r] + bias;
      }
    }
  }
}

extern "C" void kernel_launch(void* const* d_in, const int* in_sizes, int n_in,
                              void* d_out, int out_size, void* d_ws, size_t ws_size,
                              hipStream_t stream) {
  const float* x      = (const float*)d_in[0];
  const float* n1g    = (const float*)d_in[1];
  const float* n1b    = (const float*)d_in[2];
  const float* qkv_w  = (const float*)d_in[3];
  const float* qkv_b  = (const float*)d_in[4];
  const float* rtbl   = (const float*)d_in[5];
  const float* proj_w = (const float*)d_in[6];
  const float* proj_b = (const float*)d_in[7];
  const float* n2g    = (const float*)d_in[8];
  const float* n2b    = (const float*)d_in[9];
  const float* fc1_w  = (const float*)d_in[10];
  const float* fc1_b  = (const float*)d_in[11];
  const float* fc2_w  = (const float*)d_in[12];
  const float* fc2_b  = (const float*)d_in[13];
  float* out = (float*)d_out;

  if (ws_size < 221184) return;
  half_t* wbuf = (half_t*)d_ws;

  k_convert<<<432, 256, 0, stream>>>(qkv_w, proj_w, fc1_w, fc2_w, wbuf);
  k_swin<<<4096, 256, 0, stream>>>(x, n1g, n1b, wbuf, qkv_b, rtbl,
                                   wbuf + 27648, proj_b, n2g, n2b,
                                   wbuf + 36864, fc1_b, wbuf + 73728, fc2_b, out);
}

// Round 4
// 438.785 us; speedup vs baseline: 1.7753x; 1.0801x over previous
//
#include <hip/hip_runtime.h>
#include <hip/hip_fp16.h>
#include <math.h>

typedef _Float16 half_t;
typedef _Float16 half8 __attribute__((ext_vector_type(8)));
typedef float f32x4 __attribute__((ext_vector_type(4)));

#define MFMA(a, b, c) __builtin_amdgcn_mfma_f32_16x16x32_f16((a), (b), (c), 0, 0, 0)

static constexpr float kScale = 0.2041241452319315f;  // 24^-0.5
static constexpr int RS   = 104;  // hn / xn / rbuf row stride (halves; 208 B = 13*16)
static constexpr int QSTR = 200;  // qbuf row stride (400 B = 25*16)
static constexpr int VTS  = 72;   // vT row stride (144 B)
static constexpr int PS   = 72;   // pbuf row stride
static constexpr int H1S  = 392;  // h1 half row stride (784 B = 49*16)

// ---------------------------------------------------------------- weights -> fp16
__global__ __launch_bounds__(256) void k_convert(const float* __restrict__ qkv_w,
                                                 const float* __restrict__ proj_w,
                                                 const float* __restrict__ fc1_w,
                                                 const float* __restrict__ fc2_w,
                                                 half_t* __restrict__ wbuf) {
  int i = blockIdx.x * 256 + threadIdx.x;  // grid covers exactly 110592
  if (i < 27648)       wbuf[i] = (half_t)qkv_w[i];
  else if (i < 36864)  wbuf[i] = (half_t)proj_w[i - 27648];
  else if (i < 73728)  wbuf[i] = (half_t)fc1_w[i - 36864];
  else                 wbuf[i] = (half_t)fc2_w[i - 73728];
}

// ===== whole Swin block fused, one 64-token window per 256-thread block =====
// LDS 52736 B -> 3 blocks/CU (12 waves). Phase-aliased slots:
//   Slot0 @0     25600: qbuf (P1-P3: Q|K, O over Q) / h1h (P5+: 32x392)
//   Slot1 @25600 13824: vT (P1-P2) / rbuf (P3+: residual, 64x104)
//   Slot2 @39424 13312: hn (P0-P1) / pbuf (P2, 9216) / xn (P4+)
__global__ __launch_bounds__(256, 3) void k_swin(
    const float* __restrict__ x,
    const float* __restrict__ n1g, const float* __restrict__ n1b,
    const half_t* __restrict__ qkvw, const float* __restrict__ qkv_b,
    const float* __restrict__ tbl_g, const half_t* __restrict__ projw,
    const float* __restrict__ proj_b,
    const float* __restrict__ n2g, const float* __restrict__ n2b,
    const half_t* __restrict__ fc1w, const float* __restrict__ fc1b,
    const half_t* __restrict__ fc2w, const float* __restrict__ fc2b,
    float* __restrict__ out) {
  __shared__ __attribute__((aligned(16))) unsigned char smem[52736];
  half_t* qbuf = (half_t*)smem;
  half_t* h1h  = (half_t*)smem;
  half_t* vT   = (half_t*)(smem + 25600);
  half_t* rbuf = (half_t*)(smem + 25600);
  half_t* hn   = (half_t*)(smem + 39424);
  half_t* pbuf = (half_t*)(smem + 39424);
  half_t* xn   = (half_t*)(smem + 39424);

  int tid = threadIdx.x;
  int wave = tid >> 6, lane = tid & 63;
  int l15 = lane & 15, quad = lane >> 4;
  int blk = blockIdx.x;                        // bb*64 + wh*8 + ww
  int bb = blk >> 6, wh = (blk >> 3) & 7, ww = blk & 7;

  // ---- P0: LN1, each wave owns 16 rows; LN1 out -> hn (f16)
  {
    int tok = wave * 16 + l15;
    float gg[24], bv[24];
#pragma unroll
    for (int kt = 0; kt < 3; ++kt) {
      int c0 = kt * 32 + quad * 8;
      float4 g0 = *(const float4*)(n1g + c0);
      float4 g1 = *(const float4*)(n1g + c0 + 4);
      float4 b0 = *(const float4*)(n1b + c0);
      float4 b1 = *(const float4*)(n1b + c0 + 4);
      gg[kt*8+0]=g0.x; gg[kt*8+1]=g0.y; gg[kt*8+2]=g0.z; gg[kt*8+3]=g0.w;
      gg[kt*8+4]=g1.x; gg[kt*8+5]=g1.y; gg[kt*8+6]=g1.z; gg[kt*8+7]=g1.w;
      bv[kt*8+0]=b0.x; bv[kt*8+1]=b0.y; bv[kt*8+2]=b0.z; bv[kt*8+3]=b0.w;
      bv[kt*8+4]=b1.x; bv[kt*8+5]=b1.y; bv[kt*8+6]=b1.z; bv[kt*8+7]=b1.w;
    }
    int sr = (wh * 8 + (tok >> 3) + 4) & 63;
    int sc = (ww * 8 + (tok & 7) + 4) & 63;
    const float* rp = x + ((size_t)bb * 4096 + sr * 64 + sc) * 96;
    float v[24];
    float s1 = 0.f, s2 = 0.f;
#pragma unroll
    for (int kt = 0; kt < 3; ++kt) {
      float4 a = *(const float4*)(rp + kt * 32 + quad * 8);
      float4 b = *(const float4*)(rp + kt * 32 + quad * 8 + 4);
      v[kt*8+0]=a.x; v[kt*8+1]=a.y; v[kt*8+2]=a.z; v[kt*8+3]=a.w;
      v[kt*8+4]=b.x; v[kt*8+5]=b.y; v[kt*8+6]=b.z; v[kt*8+7]=b.w;
    }
#pragma unroll
    for (int c = 0; c < 24; ++c) { s1 += v[c]; s2 += v[c] * v[c]; }
    s1 += __shfl_xor(s1, 16); s1 += __shfl_xor(s1, 32);
    s2 += __shfl_xor(s2, 16); s2 += __shfl_xor(s2, 32);
    float mu = s1 * (1.f / 96.f);
    float inv = rsqrtf(fmaxf(s2 * (1.f / 96.f) - mu * mu, 0.f) + 1e-5f);
#pragma unroll
    for (int kt = 0; kt < 3; ++kt) {
      half8 hh;
#pragma unroll
      for (int j = 0; j < 8; ++j)
        hh[j] = (half_t)((v[kt*8+j] - mu) * inv * gg[kt*8+j] + bv[kt*8+j]);
      *(half8*)(&hn[tok * RS + kt * 32 + quad * 8]) = hh;
    }
  }
  __syncthreads();

  // ---- P1: QKV GEMM (18 N-tiles round-robin over 4 waves) -> qbuf / vT
  {
    half8 af[4][3];
#pragma unroll
    for (int g = 0; g < 4; ++g)
#pragma unroll
      for (int kt = 0; kt < 3; ++kt)
        af[g][kt] = *(const half8*)(&hn[(g * 16 + l15) * RS + kt * 32 + quad * 8]);
    for (int t = wave; t < 18; t += 4) {
      half8 bf[3];
#pragma unroll
      for (int kt = 0; kt < 3; ++kt)
        bf[kt] = *(const half8*)(qkvw + (size_t)(t * 16 + l15) * 96 + kt * 32 + quad * 8);
      f32x4 acc[4] = {{0,0,0,0},{0,0,0,0},{0,0,0,0},{0,0,0,0}};
#pragma unroll
      for (int kt = 0; kt < 3; ++kt)
#pragma unroll
        for (int g = 0; g < 4; ++g)
          acc[g] = MFMA(af[g][kt], bf[kt], acc[g]);
      int col = t * 16 + l15;
      float bias = qkv_b[col];
      if (t < 12) {
        float sc_ = (t < 6) ? kScale : 1.f;
#pragma unroll
        for (int g = 0; g < 4; ++g)
#pragma unroll
          for (int r = 0; r < 4; ++r)
            qbuf[(g * 16 + quad * 4 + r) * QSTR + col] = (half_t)((acc[g][r] + bias) * sc_);
      } else {
        int vc = col - 192;
        int hd = vc / 24, c = vc - hd * 24;
#pragma unroll
        for (int g = 0; g < 4; ++g)
#pragma unroll
          for (int r = 0; r < 4; ++r)
            vT[hd * 24 * VTS + c * VTS + g * 16 + quad * 4 + r] = (half_t)(acc[g][r] + bias);
      }
    }
  }
  __syncthreads();

  // ---- P2: attention (wave = head), all-MFMA
  f32x4 oacc[4][2];
  float inv_[4][4];
  {
    int head = wave;
    const half8 z8 = {};
    half8 qa[4], kb[4], vb[2][2];
#pragma unroll
    for (int g = 0; g < 4; ++g) {
      half8 t = *(const half8*)(&qbuf[(g * 16 + l15) * QSTR + head * 24 + quad * 8]);
      qa[g] = (quad < 3) ? t : z8;   // zero K-pad 24..31 on both operands
    }
#pragma unroll
    for (int nt = 0; nt < 4; ++nt) {
      half8 t = *(const half8*)(&qbuf[(nt * 16 + l15) * QSTR + 96 + head * 24 + quad * 8]);
      kb[nt] = (quad < 3) ? t : z8;
    }
#pragma unroll
    for (int nt = 0; nt < 2; ++nt)
#pragma unroll
      for (int kt = 0; kt < 2; ++kt)
        vb[nt][kt] = *(const half8*)(&vT[head * 24 * VTS + (nt * 16 + l15) * VTS + kt * 32 + quad * 8]);

    float s[4][4][4];  // [g][nt][r]
#pragma unroll
    for (int g = 0; g < 4; ++g)
#pragma unroll
      for (int nt = 0; nt < 4; ++nt) {
        f32x4 a = {0, 0, 0, 0};
        a = MFMA(qa[g], kb[nt], a);
#pragma unroll
        for (int r = 0; r < 4; ++r) s[g][nt][r] = a[r];
      }

    // bias (L1-cached global) + shift-mask (arithmetic) + softmax
    int rj[4], jh_[4], jw_[4];
#pragma unroll
    for (int nt = 0; nt < 4; ++nt) {
      int j = nt * 16 + l15;
      jh_[nt] = j >> 3; jw_[nt] = j & 7;
      int rr = wh * 8 + jh_[nt], cc = ww * 8 + jw_[nt];
      rj[nt] = ((rr < 56) ? 0 : ((rr < 60) ? 1 : 2)) * 3 + ((cc < 56) ? 0 : ((cc < 60) ? 1 : 2));
    }
#pragma unroll
    for (int g = 0; g < 4; ++g)
#pragma unroll
      for (int r = 0; r < 4; ++r) {
        int i = g * 16 + quad * 4 + r;
        int ih = i >> 3, iw = i & 7;
        int rr = wh * 8 + ih, cc = ww * 8 + iw;
        int ri = ((rr < 56) ? 0 : ((rr < 60) ? 1 : 2)) * 3 + ((cc < 56) ? 0 : ((cc < 60) ? 1 : 2));
#pragma unroll
        for (int nt = 0; nt < 4; ++nt) {
          float val = s[g][nt][r] +
              tbl_g[((ih - jh_[nt] + 7) * 15 + (iw - jw_[nt] + 7)) * 4 + head];
          if (ri != rj[nt]) val -= 100.f;
          s[g][nt][r] = val;
        }
        float mx = fmaxf(fmaxf(s[g][0][r], s[g][1][r]), fmaxf(s[g][2][r], s[g][3][r]));
        mx = fmaxf(mx, __shfl_xor(mx, 1));
        mx = fmaxf(mx, __shfl_xor(mx, 2));
        mx = fmaxf(mx, __shfl_xor(mx, 4));
        mx = fmaxf(mx, __shfl_xor(mx, 8));
        float sum = 0.f;
#pragma unroll
        for (int nt = 0; nt < 4; ++nt) {
          float e = __expf(s[g][nt][r] - mx);
          s[g][nt][r] = e;
          sum += e;
        }
        sum += __shfl_xor(sum, 1);
        sum += __shfl_xor(sum, 2);
        sum += __shfl_xor(sum, 4);
        sum += __shfl_xor(sum, 8);
        inv_[g][r] = 1.f / sum;
      }

    // PV via quarter-size wave-private P buffer (C-layout -> A-layout), 16 rows/round
    half_t* pb = pbuf + head * 16 * PS;
#pragma unroll
    for (int q4 = 0; q4 < 4; ++q4) {
#pragma unroll
      for (int nt = 0; nt < 4; ++nt)
#pragma unroll
        for (int r = 0; r < 4; ++r)
          pb[(quad * 4 + r) * PS + nt * 16 + l15] = (half_t)s[q4][nt][r];
      half8 pa[2];
#pragma unroll
      for (int kt = 0; kt < 2; ++kt)
        pa[kt] = *(const half8*)(&pb[l15 * PS + kt * 32 + quad * 8]);
#pragma unroll
      for (int nt = 0; nt < 2; ++nt) {
        f32x4 a = {0, 0, 0, 0};
#pragma unroll
        for (int kt = 0; kt < 2; ++kt) a = MFMA(pa[kt], vb[nt][kt], a);
        oacc[q4][nt] = a;
      }
    }
  }
  __syncthreads();  // all waves' Q/K reads complete before O overwrites qbuf
  {
    int head = wave;
#pragma unroll
    for (int q4 = 0; q4 < 4; ++q4)
#pragma unroll
      for (int nt = 0; nt < 2; ++nt)
#pragma unroll
        for (int r = 0; r < 4; ++r) {
          int c = nt * 16 + l15;
          if (c < 24)  // cols 24..31 are K-pad garbage
            qbuf[(q4 * 16 + quad * 4 + r) * QSTR + head * 24 + c] =
                (half_t)(oacc[q4][nt][r] * inv_[q4][r]);
        }
  }
  __syncthreads();

  // ---- P3: proj + residual (r = x + proj(O), f16 -> rbuf over dead vT)
  {
    half8 pa2[4][3];
#pragma unroll
    for (int g = 0; g < 4; ++g)
#pragma unroll
      for (int kt = 0; kt < 3; ++kt)
        pa2[g][kt] = *(const half8*)(&qbuf[(g * 16 + l15) * QSTR + kt * 32 + quad * 8]);
    for (int t = wave; t < 6; t += 4) {
      half8 bf[3];
#pragma unroll
      for (int kt = 0; kt < 3; ++kt)
        bf[kt] = *(const half8*)(projw + (size_t)(t * 16 + l15) * 96 + kt * 32 + quad * 8);
      f32x4 acc[4] = {{0,0,0,0},{0,0,0,0},{0,0,0,0},{0,0,0,0}};
#pragma unroll
      for (int kt = 0; kt < 3; ++kt)
#pragma unroll
        for (int g = 0; g < 4; ++g)
          acc[g] = MFMA(pa2[g][kt], bf[kt], acc[g]);
      int col = t * 16 + l15;
      float bias = proj_b[col];
#pragma unroll
      for (int g = 0; g < 4; ++g)
#pragma unroll
        for (int r = 0; r < 4; ++r) {
          int tok = g * 16 + quad * 4 + r;
          int sr = (wh * 8 + (tok >> 3) + 4) & 63;
          int sc = (ww * 8 + (tok & 7) + 4) & 63;
          size_t fidx = ((size_t)bb * 4096 + sr * 64 + sc) * 96 + col;
          rbuf[tok * RS + col] = (half_t)(x[fidx] + acc[g][r] + bias);
        }
    }
  }
  __syncthreads();

  // ---- P4: LN2 from rbuf -> xn (over dead pbuf/hn)
  {
    int r4 = wave * 16 + (lane >> 2);
    int ch = lane & 3;  // 24-col chunk
    const half_t* rp = rbuf + r4 * RS + ch * 24;
    half8 w0 = *(const half8*)(rp);
    half8 w1 = *(const half8*)(rp + 8);
    half8 w2 = *(const half8*)(rp + 16);
    float v[24];
#pragma unroll
    for (int j = 0; j < 8; ++j) {
      v[j] = (float)w0[j]; v[j + 8] = (float)w1[j]; v[j + 16] = (float)w2[j];
    }
    float s1 = 0.f, s2 = 0.f;
#pragma unroll
    for (int j = 0; j < 24; ++j) { s1 += v[j]; s2 += v[j] * v[j]; }
    s1 += __shfl_xor(s1, 1); s1 += __shfl_xor(s1, 2);
    s2 += __shfl_xor(s2, 1); s2 += __shfl_xor(s2, 2);
    float mu = s1 * (1.f / 96.f);
    float inv = rsqrtf(fmaxf(s2 * (1.f / 96.f) - mu * mu, 0.f) + 1e-5f);
    float gv[24], bb2[24];
#pragma unroll
    for (int q = 0; q < 6; ++q) {
      float4 g4 = *(const float4*)(n2g + ch * 24 + q * 4);
      float4 b4 = *(const float4*)(n2b + ch * 24 + q * 4);
      gv[q*4+0]=g4.x; gv[q*4+1]=g4.y; gv[q*4+2]=g4.z; gv[q*4+3]=g4.w;
      bb2[q*4+0]=b4.x; bb2[q*4+1]=b4.y; bb2[q*4+2]=b4.z; bb2[q*4+3]=b4.w;
    }
    half_t* op = xn + r4 * RS + ch * 24;
#pragma unroll
    for (int q = 0; q < 3; ++q) {
      half8 h;
#pragma unroll
      for (int j = 0; j < 8; ++j)
        h[j] = (half_t)((v[q*8+j] - mu) * inv * gv[q*8+j] + bb2[q*8+j]);
      *(half8*)(op + q * 8) = h;
    }
  }
  __syncthreads();

  // ---- P5/P6: MLP in two 32-row halves; h1h (32x392) aliases dead qbuf
  for (int hb = 0; hb < 2; ++hb) {
    {  // P5: fc1 + GELU(exact)
      half8 a5[2][3];
#pragma unroll
      for (int g2 = 0; g2 < 2; ++g2)
#pragma unroll
        for (int kt = 0; kt < 3; ++kt)
          a5[g2][kt] = *(const half8*)(&xn[((hb * 2 + g2) * 16 + l15) * RS + kt * 32 + quad * 8]);
      for (int t = wave; t < 24; t += 4) {
        int n0 = t * 16 + l15;
        half8 bf[3];
#pragma unroll
        for (int kt = 0; kt < 3; ++kt)
          bf[kt] = *(const half8*)(fc1w + (size_t)n0 * 96 + kt * 32 + quad * 8);
        f32x4 acc[2] = {{0,0,0,0},{0,0,0,0}};
#pragma unroll
        for (int kt = 0; kt < 3; ++kt)
#pragma unroll
          for (int g2 = 0; g2 < 2; ++g2)
            acc[g2] = MFMA(a5[g2][kt], bf[kt], acc[g2]);
        float bias = fc1b[n0];
#pragma unroll
        for (int g2 = 0; g2 < 2; ++g2)
#pragma unroll
          for (int r = 0; r < 4; ++r) {
            float vv = acc[g2][r] + bias;
            vv = 0.5f * vv * (1.f + erff(vv * 0.70710678118f));
            h1h[(g2 * 16 + quad * 4 + r) * H1S + n0] = (half_t)vv;
          }
      }
    }
    __syncthreads();
    {  // P6: fc2 + residual -> out
      int rt = wave >> 1, chh = wave & 1;
      half8 a2[12];
#pragma unroll
      for (int kt = 0; kt < 12; ++kt)
        a2[kt] = *(const half8*)(&h1h[(rt * 16 + l15) * H1S + kt * 32 + quad * 8]);
#pragma unroll
      for (int i = 0; i < 3; ++i) {
        int t = chh * 3 + i;
        f32x4 acc = {0, 0, 0, 0};
#pragma unroll
        for (int kt = 0; kt < 12; ++kt) {
          half8 bf = *(const half8*)(fc2w + (size_t)(t * 16 + l15) * 384 + kt * 32 + quad * 8);
          acc = MFMA(a2[kt], bf, acc);
        }
        int col = t * 16 + l15;
        float bias = fc2b[col];
#pragma unroll
        for (int r = 0; r < 4; ++r) {
          int tok = hb * 32 + rt * 16 + quad * 4 + r;
          int sr = (wh * 8 + (tok >> 3) + 4) & 63;
          int sc = (ww * 8 + (tok & 7) + 4) & 63;
          size_t fidx = ((size_t)bb * 4096 + sr * 64 + sc) * 96 + col;
          out[fidx] = (float)rbuf[tok * RS + col] + acc[r] + bias;
        }
      }
    }
    __syncthreads();
  }
}

extern "C" void kernel_launch(void* const* d_in, const int* in_sizes, int n_in,
                              void* d_out, int out_size, void* d_ws, size_t ws_size,
                              hipStream_t stream) {
  const float* x      = (const float*)d_in[0];
  const float* n1g    = (const float*)d_in[1];
  const float* n1b    = (const float*)d_in[2];
  const float* qkv_w  = (const float*)d_in[3];
  const float* qkv_b  = (const float*)d_in[4];
  const float* rtbl   = (const float*)d_in[5];
  const float* proj_w = (const float*)d_in[6];
  const float* proj_b = (const float*)d_in[7];
  const float* n2g    = (const float*)d_in[8];
  const float* n2b    = (const float*)d_in[9];
  const float* fc1_w  = (const float*)d_in[10];
  const float* fc1_b  = (const float*)d_in[11];
  const float* fc2_w  = (const float*)d_in[12];
  const float* fc2_b  = (const float*)d_in[13];
  float* out = (float*)d_out;

  if (ws_size < 221184) return;
  half_t* wbuf = (half_t*)d_ws;

  k_convert<<<432, 256, 0, stream>>>(qkv_w, proj_w, fc1_w, fc2_w, wbuf);
  k_swin<<<4096, 256, 0, stream>>>(x, n1g, n1b, wbuf, qkv_b, rtbl,
                                   wbuf + 27648, proj_b, n2g, n2b,
                                   wbuf + 36864, fc1_b, wbuf + 73728, fc2_b, out);
}